// Round 7
// baseline (234.608 us; speedup 1.0000x reference)
//
#include <hip/hip_runtime.h>

#define B_   512
#define N_   512
#define FIN_ 2
#define F_   128
#define G_   512           // 4*F gates
#define XSTRIDE 1040       // floats per x row in LDS (pad -> disjoint banks)
#define HSTRIDE 160        // halfs per h row (320B stride -> rows on disjoint bank halves)

typedef _Float16 half8  __attribute__((ext_vector_type(8)));
typedef float    float4_ __attribute__((ext_vector_type(4)));
typedef float    float2_ __attribute__((ext_vector_type(2)));

#define LOG2E_  1.44269504f
#define LOG2E2_ 2.88539008f

// One LSTM step, two batch rows per block mapped to MFMA A-rows 0 and 4.
// C layout (m89): col=lane&15, row=(lane>>4)*4+reg. A-row hrow(c15) pattern
// repeats with period 8, so C rows 8,12 (lanes 32-63 reg0) are exact DUPS of
// rows 0,4 -> gate math branchless on all 64 lanes (dup stores benign).
// Per-wave K-slice rotation (rotofs): register slot i holds k-slice (i^rot),
// permuted consistently in wf (load-time) and af (address XOR) so SIMD
// partner waves stall on different slices -> issue interleaves, not lockstep.
template<bool PF>
__device__ __forceinline__ void lstm_step(
    const _Float16* hsrc,            // per-lane: h_lds[buf] + hrow*HSTRIDE
    _Float16* hdst,                  // per-lane write slot
    float* outp,                     // per-lane HBM slot
    const half8 (&wf)[4][4], const float (&w0r)[4], const float (&w1r)[4],
    const float (&br)[4], float4_ (&acc)[4], float2_ xv,
    float& cs, int grp, int rotofs,
    const float* xpf, float2_& pf1, float2_& pf2)
{
    // A-fragments first (longest latency); slot i = k-slice (i^rot).
    half8 af[4];
#pragma unroll
    for (int i = 0; i < 4; ++i)
        af[i] = *reinterpret_cast<const half8*>(hsrc + ((i * 32) ^ rotofs) + grp * 8);

    // x prefetch for future steps: issued after af reads, before MFMAs, so
    // it's long done when the pre-barrier lgkmcnt(0) fires.
    if (PF) {
        pf1 = *reinterpret_cast<const float2_*>(xpf);
        pf2 = *reinterpret_cast<const float2_*>(xpf + 2);
    }

    // C-init reg0 = per-row x-projection + bias (fp32 exact); regs 1-3 stale.
#pragma unroll
    for (int t = 0; t < 4; ++t)
        acc[t][0] = fmaf(xv[0], w0r[t], fmaf(xv[1], w1r[t], br[t]));

    // h @ Wh: slices 0..2 natural tile order; final slice ordered {g,i,f,o}
    // so the cs-critical gate chain starts ~3 MFMAs earlier.
#pragma unroll
    for (int i = 0; i < 3; ++i)
#pragma unroll
        for (int t = 0; t < 4; ++t)
            acc[t] = __builtin_amdgcn_mfma_f32_16x16x32_f16(af[i], wf[t][i], acc[t], 0, 0, 0);
    acc[2] = __builtin_amdgcn_mfma_f32_16x16x32_f16(af[3], wf[2][3], acc[2], 0, 0, 0);
    acc[0] = __builtin_amdgcn_mfma_f32_16x16x32_f16(af[3], wf[0][3], acc[0], 0, 0, 0);
    acc[1] = __builtin_amdgcn_mfma_f32_16x16x32_f16(af[3], wf[1][3], acc[1], 0, 0, 0);
    acc[3] = __builtin_amdgcn_mfma_f32_16x16x32_f16(af[3], wf[3][3], acc[3], 0, 0, 0);

    // Gate math, g-first: chain = exp2_g -> rcp_g -> cs fma -> exp2_c -> rcp_c -> h.
    const float eg = __builtin_amdgcn_exp2f(LOG2E2_ * acc[2][0]);
    const float ei = __builtin_amdgcn_exp2f(-LOG2E_ * acc[0][0]);
    const float ef = __builtin_amdgcn_exp2f(-LOG2E_ * acc[1][0]);
    const float rg = __builtin_amdgcn_rcpf(1.f + eg);   // (1-tanh(g))/2 form
    const float ri = __builtin_amdgcn_rcpf(1.f + ei);   // sigmoid(i)
    const float rf = __builtin_amdgcn_rcpf(1.f + ef);   // sigmoid(f)
    const float gg = fmaf(-2.f, rg, 1.f);               // tanh(g)
    cs = fmaf(rf, cs, ri * gg);
    const float eo = __builtin_amdgcn_exp2f(-LOG2E_ * acc[3][0]);  // off-path
    const float ec = __builtin_amdgcn_exp2f(LOG2E2_ * cs);
    const float ro = __builtin_amdgcn_rcpf(1.f + eo);   // sigmoid(o)
    const float rc = __builtin_amdgcn_rcpf(1.f + ec);
    const float h = fmaf(-2.f * ro, rc, ro);            // o * tanh(cs)
    *hdst = (_Float16)h;              // LDS write first: it gates the barrier
    *outp = h;                        // fire-and-forget; nothing waits vmcnt
    // LDS-visibility-only barrier: never drain vmcnt in the loop.
    asm volatile("s_waitcnt lgkmcnt(0)\n\ts_barrier" ::: "memory");
}

__global__ void __launch_bounds__(512)
lstm_scan(const float* __restrict__ inp, const float* __restrict__ Wk,
          const float* __restrict__ bias, float* __restrict__ out)
{
    const int bb   = blockIdx.x;       // batch rows 2bb, 2bb+1
    const int tid  = threadIdx.x;
    const int w    = tid >> 6;         // wave 0..7, dims [w*16, w*16+16)
    const int lane = tid & 63;
    const int c15  = lane & 15;
    const int grp  = lane >> 4;        // k-group (8 consecutive k)
    // K-slice rotation parity: differs across both plausible SIMD pairings
    // ((w,w+4) and (2k,2k+1)).
    const int rotofs = ((((w >> 2) ^ w) & 1) != 0) ? 64 : 0;   // rot*32 halfs

    __shared__ __align__(64) _Float16 h_lds[2][2 * HSTRIDE];  // ping-pong h
    __shared__ __align__(64) float    x_lds[2 * XSTRIDE];     // staged inputs

    // ---- one-time: weight fragments into registers (64 VGPRs) ----
    // tile t = gate t, col = t*128 + w*16 + c15; slot i holds k-slice (i^rot)
    half8 wf[4][4];
    float w0r[4], w1r[4], br[4];
#pragma unroll
    for (int t = 0; t < 4; ++t) {
        const int col = t * F_ + w * 16 + c15;
        w0r[t] = Wk[col];
        w1r[t] = Wk[G_ + col];
        br[t]  = bias[col];
#pragma unroll
        for (int i = 0; i < 4; ++i) {
            half8 f;
#pragma unroll
            for (int e = 0; e < 8; ++e)
                f[e] = (_Float16)Wk[(size_t)(2 + ((i * 32) ^ rotofs) + grp * 8 + e) * G_ + col];
            wf[t][i] = f;
        }
    }

    // ---- stage x (2 rows x 1024 floats) into padded LDS ----
    {
        const float* xsrc = inp + (size_t)(2 * bb) * (N_ * FIN_);
        const int i4 = tid * 4;                      // 0..2044
        float4_ v = *reinterpret_cast<const float4_*>(xsrc + i4);
        const int row = i4 >> 10, idx = i4 & 1023;
        *reinterpret_cast<float4_*>(&x_lds[row * XSTRIDE + idx]) = v;
    }
    for (int i = tid; i < 2 * 2 * HSTRIDE; i += 512)
        ((_Float16*)h_lds)[i] = (_Float16)0.f;
    __syncthreads();

    const int r    = (lane >> 4) & 1;   // batch sub-row this lane handles
    const int hrow = (c15 >> 2) & 1;    // h-row feeding this lane's A slot

    const _Float16* hr0 = &h_lds[0][hrow * HSTRIDE];
    const _Float16* hr1 = &h_lds[1][hrow * HSTRIDE];
    _Float16* hw0 = &h_lds[0][r * HSTRIDE + w * 16 + c15];
    _Float16* hw1 = &h_lds[1][r * HSTRIDE + w * 16 + c15];
    const float* xq = &x_lds[r * XSTRIDE];   // x for step s lives at xq[2(s-1)]
    float* outp = out + (size_t)(2 * bb + r) * N_ * F_ + w * 16 + c15;

    float cs = 0.f;
    float4_ acc[4];
#pragma unroll
    for (int t = 0; t < 4; ++t) { acc[t][0] = 0.f; acc[t][1] = 0.f; acc[t][2] = 0.f; acc[t][3] = 0.f; }

    float2_ xz; xz[0] = 0.f; xz[1] = 0.f;
    float2_ pf1, pf2;

    // step 0: x_shift = 0, reads zeroed buf0, writes buf1; prefetch x(1,2)
    lstm_step<true>(hr0, hw1, outp, wf, w0r, w1r, br, acc, xz, cs, grp, rotofs,
                    xq, pf1, pf2);
    outp += F_;

    // steps 1..510 in pairs (odd reads buf1, even reads buf0)
    for (int i = 0; i < 255; ++i) {
        const float2_ xv1 = pf1;          // x for step 2i+1
        const float2_ xv2 = pf2;          // x for step 2i+2
        // first step of pair prefetches x for steps 2i+3, 2i+4
        lstm_step<true>(hr1, hw0, outp, wf, w0r, w1r, br, acc, xv1, cs, grp,
                        rotofs, xq + 4 * i + 4, pf1, pf2);
        outp += F_;
        lstm_step<false>(hr0, hw1, outp, wf, w0r, w1r, br, acc, xv2, cs, grp,
                         rotofs, nullptr, pf1, pf2);
        outp += F_;
    }
    // step 511 (odd): reads buf1; pf1 = x for step 511
    lstm_step<false>(hr1, hw0, outp, wf, w0r, w1r, br, acc, pf1, cs, grp,
                     rotofs, nullptr, pf1, pf2);
}

extern "C" void kernel_launch(void* const* d_in, const int* in_sizes, int n_in,
                              void* d_out, int out_size, void* d_ws, size_t ws_size,
                              hipStream_t stream) {
    const float* inp  = (const float*)d_in[0];
    const float* Wk   = (const float*)d_in[1];
    const float* bias = (const float*)d_in[2];
    float* out        = (float*)d_out;
    lstm_scan<<<dim3(B_ / 2), dim3(512), 0, stream>>>(inp, Wk, bias, out);
}

// Round 8
// 233.189 us; speedup vs baseline: 1.0061x; 1.0061x over previous
//
#include <hip/hip_runtime.h>

#define B_   512
#define N_   512
#define FIN_ 2
#define F_   128
#define G_   512           // 4*F gates
#define XSTRIDE 1040       // floats per x row in LDS (pad -> disjoint banks)
#define HSTRIDE 160        // halfs per h row (320B stride -> rows on disjoint bank halves)

typedef _Float16 half8  __attribute__((ext_vector_type(8)));
typedef float    float4_ __attribute__((ext_vector_type(4)));
typedef float    float2_ __attribute__((ext_vector_type(2)));

#define LOG2E_  1.44269504f
#define LOG2E2_ 2.88539008f

// One LSTM step, two batch rows per block mapped to MFMA A-rows 0 and 4.
// C layout (m89): col=lane&15, row=(lane>>4)*4+reg. A-row hrow(c15) pattern
// repeats with period 8, so C rows 8,12 (lanes 32-63 reg0) are exact DUPS of
// rows 0,4 -> gate math branchless on all 64 lanes (dup stores benign).
template<bool PF>
__device__ __forceinline__ void lstm_step(
    const _Float16* hsrc,            // per-lane: h_lds[buf] + hrow*HSTRIDE
    _Float16* hdst,                  // per-lane write slot
    float* outp,                     // per-lane HBM slot
    const half8 (&wf)[4][4], const float (&w0r)[4], const float (&w1r)[4],
    const float (&br)[4], float4_ (&acc)[4], float2_ xv,
    float& cs, int grp,
    const float* xpf, float2_& pf1, float2_& pf2)
{
    // A-fragments first (longest latency).
    half8 af[4];
#pragma unroll
    for (int i = 0; i < 4; ++i)
        af[i] = *reinterpret_cast<const half8*>(hsrc + i * 32 + grp * 8);

    // x prefetch for future steps: issued after af reads, before MFMAs, so
    // it's long done when the pre-barrier lgkmcnt(0) fires.
    if (PF) {
        pf1 = *reinterpret_cast<const float2_*>(xpf);
        pf2 = *reinterpret_cast<const float2_*>(xpf + 2);
    }

    // C-init reg0 = per-row x-projection + bias (fp32 exact); regs 1-3 stale.
#pragma unroll
    for (int t = 0; t < 4; ++t)
        acc[t][0] = fmaf(xv[0], w0r[t], fmaf(xv[1], w1r[t], br[t]));

    // h @ Wh: slices 0..2 natural tile order; final slice ordered {g,i,f,o}
    // so the cs-critical gate chain starts ~3 MFMAs earlier.
#pragma unroll
    for (int i = 0; i < 3; ++i)
#pragma unroll
        for (int t = 0; t < 4; ++t)
            acc[t] = __builtin_amdgcn_mfma_f32_16x16x32_f16(af[i], wf[t][i], acc[t], 0, 0, 0);
    acc[2] = __builtin_amdgcn_mfma_f32_16x16x32_f16(af[3], wf[2][3], acc[2], 0, 0, 0);
    acc[0] = __builtin_amdgcn_mfma_f32_16x16x32_f16(af[3], wf[0][3], acc[0], 0, 0, 0);
    acc[1] = __builtin_amdgcn_mfma_f32_16x16x32_f16(af[3], wf[1][3], acc[1], 0, 0, 0);
    acc[3] = __builtin_amdgcn_mfma_f32_16x16x32_f16(af[3], wf[3][3], acc[3], 0, 0, 0);

    // Gate math, g-first: chain = exp2_g -> rcp_g -> cs fma -> exp2_c -> rcp_c -> h.
    const float eg = __builtin_amdgcn_exp2f(LOG2E2_ * acc[2][0]);
    const float ei = __builtin_amdgcn_exp2f(-LOG2E_ * acc[0][0]);
    const float ef = __builtin_amdgcn_exp2f(-LOG2E_ * acc[1][0]);
    const float rg = __builtin_amdgcn_rcpf(1.f + eg);   // (1-tanh(g))/2 form
    const float ri = __builtin_amdgcn_rcpf(1.f + ei);   // sigmoid(i)
    const float rf = __builtin_amdgcn_rcpf(1.f + ef);   // sigmoid(f)
    const float gg = fmaf(-2.f, rg, 1.f);               // tanh(g)
    cs = fmaf(rf, cs, ri * gg);
    const float eo = __builtin_amdgcn_exp2f(-LOG2E_ * acc[3][0]);  // off-path
    const float ec = __builtin_amdgcn_exp2f(LOG2E2_ * cs);
    const float ro = __builtin_amdgcn_rcpf(1.f + eo);   // sigmoid(o)
    const float rc = __builtin_amdgcn_rcpf(1.f + ec);
    const float h = fmaf(-2.f * ro, rc, ro);            // o * tanh(cs)
    *hdst = (_Float16)h;              // LDS write first: it gates the barrier
    *outp = h;                        // fire-and-forget; nothing waits vmcnt
    // LDS-visibility-only barrier: never drain vmcnt in the loop.
    asm volatile("s_waitcnt lgkmcnt(0)\n\ts_barrier" ::: "memory");
}

__global__ void __launch_bounds__(512)
lstm_scan(const float* __restrict__ inp, const float* __restrict__ Wk,
          const float* __restrict__ bias, float* __restrict__ out)
{
    const int bb   = blockIdx.x;       // batch rows 2bb, 2bb+1
    const int tid  = threadIdx.x;
    const int w    = tid >> 6;         // wave 0..7, dims [w*16, w*16+16)
    const int lane = tid & 63;
    const int c15  = lane & 15;
    const int grp  = lane >> 4;        // k-group (8 consecutive k)

    __shared__ __align__(64) _Float16 h_lds[2][2 * HSTRIDE];  // ping-pong h
    __shared__ __align__(64) float    x_lds[2 * XSTRIDE];     // staged inputs

    // ---- one-time: weight fragments into registers (64 VGPRs) ----
    // tile t = gate t, col = t*128 + w*16 + c15
    half8 wf[4][4];
    float w0r[4], w1r[4], br[4];
#pragma unroll
    for (int t = 0; t < 4; ++t) {
        const int col = t * F_ + w * 16 + c15;
        w0r[t] = Wk[col];
        w1r[t] = Wk[G_ + col];
        br[t]  = bias[col];
#pragma unroll
        for (int i = 0; i < 4; ++i) {
            half8 f;
#pragma unroll
            for (int e = 0; e < 8; ++e)
                f[e] = (_Float16)Wk[(size_t)(2 + i * 32 + grp * 8 + e) * G_ + col];
            wf[t][i] = f;
        }
    }

    // ---- stage x (2 rows x 1024 floats) into padded LDS ----
    {
        const float* xsrc = inp + (size_t)(2 * bb) * (N_ * FIN_);
        const int i4 = tid * 4;                      // 0..2044
        float4_ v = *reinterpret_cast<const float4_*>(xsrc + i4);
        const int row = i4 >> 10, idx = i4 & 1023;
        *reinterpret_cast<float4_*>(&x_lds[row * XSTRIDE + idx]) = v;
    }
    for (int i = tid; i < 2 * 2 * HSTRIDE; i += 512)
        ((_Float16*)h_lds)[i] = (_Float16)0.f;
    __syncthreads();

    // ---- static asymmetric wave priority: desync SIMD-partner waves ----
    // Parity differs within a pair under both plausible wave->SIMD pairings
    // ((w,w+4) and (2k,2k+1)). Hi wave wins issue arbitration -> its MFMA
    // phase completes first and its gate tail hides under the partner's MFMA
    // phase (and vice versa), instead of both running gates simultaneously.
    if ((((w >> 2) ^ w) & 1) != 0)
        __builtin_amdgcn_s_setprio(1);   // permanent for this wave

    const int r    = (lane >> 4) & 1;   // batch sub-row this lane handles
    const int hrow = (c15 >> 2) & 1;    // h-row feeding this lane's A slot

    const _Float16* hr0 = &h_lds[0][hrow * HSTRIDE];
    const _Float16* hr1 = &h_lds[1][hrow * HSTRIDE];
    _Float16* hw0 = &h_lds[0][r * HSTRIDE + w * 16 + c15];
    _Float16* hw1 = &h_lds[1][r * HSTRIDE + w * 16 + c15];
    const float* xq = &x_lds[r * XSTRIDE];   // x for step s lives at xq[2(s-1)]
    float* outp = out + (size_t)(2 * bb + r) * N_ * F_ + w * 16 + c15;

    float cs = 0.f;
    float4_ acc[4];
#pragma unroll
    for (int t = 0; t < 4; ++t) { acc[t][0] = 0.f; acc[t][1] = 0.f; acc[t][2] = 0.f; acc[t][3] = 0.f; }

    float2_ xz; xz[0] = 0.f; xz[1] = 0.f;
    float2_ pf1, pf2;

    // step 0: x_shift = 0, reads zeroed buf0, writes buf1; prefetch x(1,2)
    lstm_step<true>(hr0, hw1, outp, wf, w0r, w1r, br, acc, xz, cs, grp,
                    xq, pf1, pf2);
    outp += F_;

    // steps 1..510 in pairs (odd reads buf1, even reads buf0)
    for (int i = 0; i < 255; ++i) {
        const float2_ xv1 = pf1;          // x for step 2i+1
        const float2_ xv2 = pf2;          // x for step 2i+2
        // first step of pair prefetches x for steps 2i+3, 2i+4
        lstm_step<true>(hr1, hw0, outp, wf, w0r, w1r, br, acc, xv1, cs, grp,
                        xq + 4 * i + 4, pf1, pf2);
        outp += F_;
        lstm_step<false>(hr0, hw1, outp, wf, w0r, w1r, br, acc, xv2, cs, grp,
                         nullptr, pf1, pf2);
        outp += F_;
    }
    // step 511 (odd): reads buf1; pf1 = x for step 511
    lstm_step<false>(hr1, hw0, outp, wf, w0r, w1r, br, acc, pf1, cs, grp,
                     nullptr, pf1, pf2);
}

extern "C" void kernel_launch(void* const* d_in, const int* in_sizes, int n_in,
                              void* d_out, int out_size, void* d_ws, size_t ws_size,
                              hipStream_t stream) {
    const float* inp  = (const float*)d_in[0];
    const float* Wk   = (const float*)d_in[1];
    const float* bias = (const float*)d_in[2];
    float* out        = (float*)d_out;
    lstm_scan<<<dim3(B_ / 2), dim3(512), 0, stream>>>(inp, Wk, bias, out);
}